// Round 20
// baseline (331.425 us; speedup 1.0000x reference)
//
#include <hip/hip_runtime.h>
#include <math.h>

// AttnBlock: GroupNorm -> q,k,v 1x1 conv -> full softmax attention over 4096
// positions -> 1x1 conv -> (x + h)/sqrt(2).
// Round 19: single-variable isolation of R17's spill. R17 bundled three
// changes (direct i32x8 loads, setprio removal, exp2f -- which fell back to
// LIBM exp2f, the likely register/VALU bomb). This round: R18 base + ONLY
// direct i32x8 loads (no V8U union round-trip); setprio fences and __expf
// kept. MX-fp8 K=64 MFMA attention, LDS-free, 1 wave/SIMD.
// B=8, H=W=64 (N=4096), C=256, G=32.

typedef __attribute__((ext_vector_type(8))) short bf16x8;
typedef __attribute__((ext_vector_type(4))) float f32x4;
typedef __attribute__((ext_vector_type(16))) float f32x16;
typedef __attribute__((ext_vector_type(8))) int i32x8;
typedef unsigned short u16;
typedef unsigned char u8;
typedef __attribute__((address_space(3))) unsigned int lds_u32;
typedef __attribute__((address_space(1))) unsigned int glb_u32;

namespace {
constexpr int Bn = 8;
constexpr int Np = 4096;                 // H*W
constexpr int Cc = 256;
constexpr float kEps = 1e-6f;
constexpr float kRsqrt2 = 0.70710678118654752440f;
constexpr int kRows = Bn * Np;           // 32768
}  // namespace

__device__ __forceinline__ u16 f2b(float x) {
  unsigned int u = __float_as_uint(x);
  u += 0x7fffu + ((u >> 16) & 1u);       // round-to-nearest-even
  return (u16)(u >> 16);
}

__device__ __forceinline__ u8 f2fp8(float x) {
  return (u8)(__builtin_amdgcn_cvt_pk_fp8_f32(x, x, 0, false) & 0xff);
}

__device__ __forceinline__ void stage16(const void* g, void* l) {
  __builtin_amdgcn_global_load_lds((const glb_u32*)g, (lds_u32*)l, 16, 0, 0);
}

union V8U {
  uint4 u[2];
  i32x8 v;
};

// ---------------- weight convert: W[c][d] fp32 -> W^T swizzled bf16 tiles ---
__global__ __launch_bounds__(256) void conv_w_k(
    const float* __restrict__ Wq, const float* __restrict__ Wk,
    const float* __restrict__ Wv, const float* __restrict__ Wf,
    u16* __restrict__ wsw) {
  const int w = blockIdx.x;
  const float* W = (w == 0) ? Wq : (w == 1) ? Wk : (w == 2) ? Wv : Wf;
  const int t = threadIdx.x;               // = d (output channel)
  const int nt = t >> 7, r = t & 127;
  for (int c0 = 0; c0 < 32; ++c0) {
    const int c = blockIdx.y * 32 + c0;
    const float val = W[(size_t)c * Cc + t];   // coalesced along t
    const int kt = c >> 6, kk = c & 63;
    const size_t byte = (((size_t)(w * 8 + nt * 4 + kt)) << 14) +
                        (((r * 128 + kk * 2)) ^ ((r & 7) << 4));
    *(u16*)((char*)wsw + byte) = f2b(val);
  }
}

// ---------------- GroupNorm (two-kernel: stats + coalesced apply) ---------
__global__ __launch_bounds__(256) void gn_stats_k(const float* __restrict__ x,
                                                  float* __restrict__ st) {
  const int bg = blockIdx.x;
  const int b = bg >> 5, g = bg & 31;
  const float* base = x + (size_t)b * Np * Cc + g * 8;
  float s = 0.f, ss = 0.f;
  for (int i = threadIdx.x; i < Np * 2; i += 256) {
    const int p = i >> 1, hh = (i & 1) * 4;
    const float4 v = *(const float4*)(base + (size_t)p * Cc + hh);
    s += v.x + v.y + v.z + v.w;
    ss += v.x * v.x + v.y * v.y + v.z * v.z + v.w * v.w;
  }
  __shared__ float red[8];
#pragma unroll
  for (int off = 32; off; off >>= 1) {
    s += __shfl_down(s, off);
    ss += __shfl_down(ss, off);
  }
  const int wid = threadIdx.x >> 6;
  if ((threadIdx.x & 63) == 0) { red[wid] = s; red[wid + 4] = ss; }
  __syncthreads();
  if (threadIdx.x == 0) {
    s = red[0] + red[1] + red[2] + red[3];
    ss = red[4] + red[5] + red[6] + red[7];
    const float mean = s * (1.f / 32768.f);
    const float var = ss * (1.f / 32768.f) - mean * mean;
    st[bg * 2] = mean;
    st[bg * 2 + 1] = rsqrtf(var + kEps);
  }
}

// gn_apply writes h as bf16 SWIZZLED GEMM A-tiles directly (coalesced read).
__global__ __launch_bounds__(256) void gn_apply_k(const float* __restrict__ x,
                                                  const float* __restrict__ st,
                                                  const float* __restrict__ gs,
                                                  const float* __restrict__ gb,
                                                  u16* __restrict__ hsw) {
  const int total = kRows * Cc / 4;
  for (int i = blockIdx.x * blockDim.x + threadIdx.x; i < total;
       i += gridDim.x * blockDim.x) {
    const int c4 = i & 63;
    const int p = i >> 6;
    const int b = p >> 12;
    const int g = c4 >> 1;
    const float mean = st[(b * 32 + g) * 2];
    const float rstd = st[(b * 32 + g) * 2 + 1];
    const float4 xv = ((const float4*)x)[i];
    const float4 sv = ((const float4*)gs)[c4];
    const float4 bv = ((const float4*)gb)[c4];
    ushort4 o;
    o.x = f2b((xv.x - mean) * rstd * sv.x + bv.x);
    o.y = f2b((xv.y - mean) * rstd * sv.y + bv.y);
    o.z = f2b((xv.z - mean) * rstd * sv.z + bv.z);
    o.w = f2b((xv.w - mean) * rstd * sv.w + bv.w);
    const int mt = p >> 7, r = p & 127;
    const int c = c4 * 4, kt = c >> 6, kk = c & 63;
    const size_t byte = (((size_t)(mt * 4 + kt)) << 14) +
                        (((r * 128 + kk * 2)) ^ ((r & 7) << 4));
    *(ushort4*)((char*)hsw + byte) = o;
  }
}

// ---------------- bf16 MFMA GEMM (A_sw [M][K] tiles, W^T_sw tiles) ---------
// mode 0: q = A.Wq + bq -> fp8 rows (UNSCALED; 1/16 folded into attn exp).
// mode 1: k -> fp8 QK-A-fragment tiles, 16KB per 64 keys.
// mode 2: v -> fp8 PV-A-fragment tiles, 16KB per 64 kv.
// mode 3: out = (x + A.Wf + bf)*rsqrt2 fp32.
__global__ __launch_bounds__(256, 2) void gemm_k(
    const u16* __restrict__ A_sw, const u16* __restrict__ wsw,
    const float* __restrict__ bq, const float* __restrict__ bk,
    const float* __restrict__ bv, const float* __restrict__ bf,
    const float* __restrict__ x, u8* __restrict__ qg, u8* __restrict__ kg,
    u8* __restrict__ vtt, float* __restrict__ out, int mode_sel) {
  __shared__ __align__(16) u16 Al[2][8192], Bl[2][8192];
  const int mode = (mode_sel < 0) ? blockIdx.z : mode_sel;
  const int mt0 = blockIdx.x;
  const int nt0 = blockIdx.y;
  const int t = threadIdx.x;
  const int w = t >> 6, l = t & 63;
  const int wm = w >> 1, wn = w & 1;
  const int lr = l & 15, lg = l >> 4;
  f32x4 acc[4][4];
#pragma unroll
  for (int i = 0; i < 4; ++i)
#pragma unroll
    for (int j = 0; j < 4; ++j) acc[i][j] = (f32x4){0.f, 0.f, 0.f, 0.f};

  auto stg = [&](int kt, int nxt) {
    const char* at = (const char*)A_sw + (((size_t)mt0 * 4 + kt) << 14);
    const char* bt =
        (const char*)wsw + (((size_t)(mode * 8 + nt0 * 4 + kt)) << 14);
    char* ad = (char*)&Al[nxt][0];
    char* bd = (char*)&Bl[nxt][0];
#pragma unroll
    for (int p = 0; p < 4; ++p) {
      const int c = p * 256 + t;
      stage16(at + c * 16, ad + c * 16);
      stage16(bt + c * 16, bd + c * 16);
    }
  };

  stg(0, 0);
  __syncthreads();
  for (int kt = 0; kt < 4; ++kt) {
    if (kt < 3) stg(kt + 1, (kt + 1) & 1);
    const char* Ac = (const char*)&Al[kt & 1][0];
    const char* Bc = (const char*)&Bl[kt & 1][0];
    __builtin_amdgcn_s_setprio(1);
#pragma unroll
    for (int ks = 0; ks < 2; ++ks) {
      bf16x8 af[4], bfr[4];
#pragma unroll
      for (int i = 0; i < 4; ++i)
        af[i] = *(const bf16x8*)(
            Ac + (((wm * 64 + i * 16 + lr) * 128 + ks * 64 + lg * 16) ^
                  ((lr & 7) << 4)));
#pragma unroll
      for (int j = 0; j < 4; ++j)
        bfr[j] = *(const bf16x8*)(
            Bc + (((wn * 64 + j * 16 + lr) * 128 + ks * 64 + lg * 16) ^
                  ((lr & 7) << 4)));
#pragma unroll
      for (int i = 0; i < 4; ++i)
#pragma unroll
        for (int j = 0; j < 4; ++j)
          acc[i][j] = __builtin_amdgcn_mfma_f32_16x16x32_bf16(af[i], bfr[j],
                                                              acc[i][j], 0, 0, 0);
    }
    __builtin_amdgcn_s_setprio(0);
    __syncthreads();
  }
  // ---- epilogue ----
  const int m0 = mt0 * 128 + wm * 64;
  const int n0 = nt0 * 128 + wn * 64;
  const float* bias = (mode == 0) ? bq : (mode == 1) ? bk : (mode == 2) ? bv : bf;
  float bv4[4];
#pragma unroll
  for (int j = 0; j < 4; ++j) bv4[j] = bias[n0 + j * 16 + lr];
#pragma unroll
  for (int i = 0; i < 4; ++i)
#pragma unroll
    for (int e = 0; e < 4; ++e) {
      const int m = m0 + i * 16 + lg * 4 + e;
#pragma unroll
      for (int j = 0; j < 4; ++j) {
        const int n = n0 + j * 16 + lr;
        const float val = acc[i][j][e] + bv4[j];
        if (mode == 0) {
          qg[(size_t)m * Cc + n] = f2fp8(val);
        } else if (mode == 1) {
          const size_t pos = ((size_t)(m >> 6)) * 16384 +
                             ((size_t)((m >> 5) & 1)) * 8192 +
                             (n >> 6) * 2048 +
                             ((m & 31) + 32 * ((n >> 5) & 1)) * 32 + (n & 31);
          kg[pos] = f2fp8(val);
        } else if (mode == 2) {
          const int kv = m & 63;
          const size_t pos = ((size_t)(m >> 6)) * 16384 + (n >> 5) * 2048 +
                             ((n & 31) + 32 * ((kv >> 2) & 1)) * 32 +
                             (kv & 3) + 4 * ((kv & 31) >> 3) + 16 * (kv >> 5);
          vtt[pos] = f2fp8(val);
        } else {
          out[(size_t)m * Cc + n] =
              (x[(size_t)m * Cc + n] + val) * kRsqrt2;
        }
      }
    }
}

// ---------------- LDS-free MX-fp8 attention, K-dbuf + SM||QK overlap ------
// Grid: 1024 blocks x 64 threads (1 wave). id: batch = id&7 (XCD pin),
// q-tile (32 rows) = id>>3. 64 key-tiles of 64 keys. Per tile: 8 QK + 8 PV
// mfma_scale_32x32x64 (scale=1.0). K register-double-buffered so QK(t+1)
// sits after SM(t) in one basic block. THIS ROUND: direct i32x8 loads
// (isolating R17's load change; setprio + __expf kept).
// p = exp(s/16 - 2) no-max softmax (validated R5+).
__global__ __launch_bounds__(64, 1) void attn_mfma_k(
    const u8* __restrict__ qg, const u8* __restrict__ ksw,
    const u8* __restrict__ vsw, u16* __restrict__ h2) {
  const int id = blockIdx.x;
  const int b = id & 7;
  const int qt = id >> 3;                 // 0..127
  const int l = threadIdx.x;
  const int lq = l & 31;
  const int hi = l >> 5;

  const u8* kbase = ksw + (size_t)b * Np * Cc;
  const u8* vbase = vsw + (size_t)b * Np * Cc;

  // Q fragments: MFMA m covers channels m*64 + hi*32 + (0..31)
  i32x8 QF[4];
  {
    const u8* qrow = qg + ((size_t)b * Np + qt * 32 + lq) * Cc;
#pragma unroll
    for (int m = 0; m < 4; ++m)
      QF[m] = *(const i32x8*)(qrow + m * 64 + hi * 32);
  }
  f32x16 oacc[8];
#pragma unroll
  for (int nb = 0; nb < 8; ++nb)
#pragma unroll
    for (int r = 0; r < 16; ++r) oacc[nb][r] = 0.f;
  float lrow = 0.f;

  i32x8 KA[8], KB[8], VRr[8];   // K: [ (s<<2)|m ]; V: [cb]

  auto loadK = [&](int gt, i32x8* K) {
    const u8* kt = kbase + (size_t)gt * 16384;
#pragma unroll
    for (int i = 0; i < 8; ++i)
      K[i] = *(const i32x8*)(kt + (i >> 2) * 8192 + (i & 3) * 2048 + l * 32);
  };
  auto loadV = [&](int gt) {
    const u8* vt = vbase + (size_t)gt * 16384;
#pragma unroll
    for (int cb = 0; cb < 8; ++cb)
      VRr[cb] = *(const i32x8*)(vt + cb * 2048 + l * 32);
  };

  // QK: S^T[64 key][32 q], two 4-MFMA chains over 256 channels.
  auto qk = [&](const i32x8* K, f32x16& s0, f32x16& s1) {
#pragma unroll
    for (int r = 0; r < 16; ++r) { s0[r] = 0.f; s1[r] = 0.f; }
    __builtin_amdgcn_s_setprio(1);
#pragma unroll
    for (int m = 0; m < 4; ++m) {
      s0 = __builtin_amdgcn_mfma_scale_f32_32x32x64_f8f6f4(
          K[m], QF[m], s0, 0, 0, 0, 0x7F, 0, 0x7F);
      s1 = __builtin_amdgcn_mfma_scale_f32_32x32x64_f8f6f4(
          K[4 + m], QF[m], s1, 0, 0, 0, 0x7F, 0, 0x7F);
    }
    __builtin_amdgcn_s_setprio(0);
  };

  // softmax + pack: p = exp(s/16 - 2); bytes 0-15 = p0, 16-31 = p1.
  auto smpack = [&](const f32x16& s0, const f32x16& s1, V8U& PP) {
    unsigned int d[8];
#pragma unroll
    for (int g = 0; g < 4; ++g) {
      const float a0 = __expf(s0[4 * g + 0] * 0.0625f - 2.0f);
      const float a1 = __expf(s0[4 * g + 1] * 0.0625f - 2.0f);
      const float a2 = __expf(s0[4 * g + 2] * 0.0625f - 2.0f);
      const float a3 = __expf(s0[4 * g + 3] * 0.0625f - 2.0f);
      lrow += (a0 + a1) + (a2 + a3);
      unsigned int r0 = (unsigned int)__builtin_amdgcn_cvt_pk_fp8_f32(
          a0, a1, 0, false);
      d[g] = (unsigned int)__builtin_amdgcn_cvt_pk_fp8_f32(a2, a3, (int)r0,
                                                           true);
      const float b0 = __expf(s1[4 * g + 0] * 0.0625f - 2.0f);
      const float b1 = __expf(s1[4 * g + 1] * 0.0625f - 2.0f);
      const float b2 = __expf(s1[4 * g + 2] * 0.0625f - 2.0f);
      const float b3 = __expf(s1[4 * g + 3] * 0.0625f - 2.0f);
      lrow += (b0 + b1) + (b2 + b3);
      unsigned int r1 = (unsigned int)__builtin_amdgcn_cvt_pk_fp8_f32(
          b0, b1, 0, false);
      d[4 + g] = (unsigned int)__builtin_amdgcn_cvt_pk_fp8_f32(b2, b3, (int)r1,
                                                               true);
    }
    PP.u[0] = make_uint4(d[0], d[1], d[2], d[3]);
    PP.u[1] = make_uint4(d[4], d[5], d[6], d[7]);
  };

  // PV: O^T[256 ch][32 q] += V^T * P^T (8 independent MFMAs)
  auto pv = [&](const V8U& PP) {
    __builtin_amdgcn_s_setprio(1);
#pragma unroll
    for (int cb = 0; cb < 8; ++cb) {
      oacc[cb] = __builtin_amdgcn_mfma_scale_f32_32x32x64_f8f6f4(
          VRr[cb], PP.v, oacc[cb], 0, 0, 0, 0x7F, 0, 0x7F);
    }
    __builtin_amdgcn_s_setprio(0);
  };

  f32x16 sA0, sA1, sB0, sB1;
  loadK(0, KA);
  loadV(0);
  qk(KA, sA0, sA1);                       // QK(0)
  loadK(1, KB);

  // loop invariant at top: sA = QK(t), KB = K(t+1), VRr = V(t).
  for (int t = 0; t <= 60; t += 2) {
    V8U PP;
    smpack(sA0, sA1, PP);                 // SM(t)   (VALU)
    qk(KB, sB0, sB1);                     // QK(t+1) (MFMA, overlaps SM)
    pv(PP);                               // PV(t)
    loadV(t + 1);
    loadK(t + 2, KA);                     // KA free since QK(t)
    smpack(sB0, sB1, PP);                 // SM(t+1)
    qk(KA, sA0, sA1);                     // QK(t+2)
    pv(PP);                               // PV(t+1)
    loadV(t + 2);
    loadK(t + 3, KB);
  }
  // exit: sA = QK(62), KB = K(63), VRr = V(62).
  {
    V8U PP;
    smpack(sA0, sA1, PP);                 // SM(62)
    qk(KB, sB0, sB1);                     // QK(63)
    pv(PP);                               // PV(62)
    loadV(63);
    smpack(sB0, sB1, PP);                 // SM(63)
    pv(PP);                               // PV(63)
  }

  // ---- epilogue: normalize, store bf16 swizzled A-tiles for final GEMM ----
  lrow += __shfl_xor(lrow, 32);
  const float inv = 1.f / lrow;
  const size_t mt = (size_t)b * 32 + (qt >> 2);
  const int r = (qt & 3) * 32 + lq;
#pragma unroll
  for (int nb = 0; nb < 8; ++nb)
#pragma unroll
    for (int g = 0; g < 4; ++g) {
      const int c = nb * 32 + g * 8 + hi * 4;
      const int kt = c >> 6, kk = c & 63;
      ushort4 val;
      val.x = f2b(oacc[nb][4 * g + 0] * inv);
      val.y = f2b(oacc[nb][4 * g + 1] * inv);
      val.z = f2b(oacc[nb][4 * g + 2] * inv);
      val.w = f2b(oacc[nb][4 * g + 3] * inv);
      const size_t byte =
          ((mt * 4 + kt) << 14) + (((r * 128 + kk * 2)) ^ ((r & 7) << 4));
      *(ushort4*)((char*)h2 + byte) = val;
    }
}

extern "C" void kernel_launch(void* const* d_in, const int* in_sizes, int n_in,
                              void* d_out, int out_size, void* d_ws,
                              size_t ws_size, hipStream_t stream) {
  const float* x = (const float*)d_in[0];
  const float* gs = (const float*)d_in[1];
  const float* gb = (const float*)d_in[2];
  const float* Wq = (const float*)d_in[3];
  const float* bq = (const float*)d_in[4];
  const float* Wk = (const float*)d_in[5];
  const float* bk = (const float*)d_in[6];
  const float* Wv = (const float*)d_in[7];
  const float* bv = (const float*)d_in[8];
  const float* Wf = (const float*)d_in[9];
  const float* bf = (const float*)d_in[10];
  float* out = (float*)d_out;

  // ws: h_sw bf16 | q fp8 | k_sw fp8 | v_sw fp8 | h2_sw bf16 | wsw bf16 | st
  u16* hsw = (u16*)d_ws;
  u8* qg = (u8*)(hsw + (size_t)kRows * Cc);
  u8* kg = qg + (size_t)kRows * Cc;
  u8* vtt = kg + (size_t)kRows * Cc;
  u16* h2 = (u16*)(vtt + (size_t)kRows * Cc);
  u16* wsw = h2 + (size_t)kRows * Cc;
  float* st = (float*)(wsw + 4 * 8 * 8192);

  conv_w_k<<<dim3(4, 8), dim3(256), 0, stream>>>(Wq, Wk, Wv, Wf, wsw);
  gn_stats_k<<<dim3(Bn * 32), dim3(256), 0, stream>>>(x, st);
  gn_apply_k<<<dim3(1024), dim3(256), 0, stream>>>(x, st, gs, gb, hsw);
  gemm_k<<<dim3(kRows / 128, Cc / 128, 3), dim3(256), 0, stream>>>(
      hsw, wsw, bq, bk, bv, bf, x, qg, kg, vtt, out, -1);
  attn_mfma_k<<<dim3(1024), dim3(64), 0, stream>>>(qg, kg, vtt, h2);
  gemm_k<<<dim3(kRows / 128, Cc / 128, 1), dim3(256), 0, stream>>>(
      h2, wsw, bq, bk, bv, bf, x, qg, kg, vtt, out, 3);
}

// Round 21
// 197.168 us; speedup vs baseline: 1.6809x; 1.6809x over previous
//
#include <hip/hip_runtime.h>
#include <math.h>

// AttnBlock: GroupNorm -> q,k,v 1x1 conv -> full softmax attention over 4096
// positions -> 1x1 conv -> (x + h)/sqrt(2).
// Round 20: pure revert to R18 (best: 197.3us). R19 isolated the spill
// trigger: direct i32x8 loads force contiguous 8-VGPR allocation at load
// time -> allocator can't tile the file -> 256 cap + scratch. The V8U union
// (two independent dwordx4 tuples, late coalescing) is REQUIRED at this
// register pressure. Attention: LDS-free MX-fp8 K=64 MFMA, K-dbuf,
// SM||QK overlap, setprio fences, __expf softmax, 188 VGPR, 1 wave/SIMD.
// B=8, H=W=64 (N=4096), C=256, G=32.

typedef __attribute__((ext_vector_type(8))) short bf16x8;
typedef __attribute__((ext_vector_type(4))) float f32x4;
typedef __attribute__((ext_vector_type(16))) float f32x16;
typedef __attribute__((ext_vector_type(8))) int i32x8;
typedef unsigned short u16;
typedef unsigned char u8;
typedef __attribute__((address_space(3))) unsigned int lds_u32;
typedef __attribute__((address_space(1))) unsigned int glb_u32;

namespace {
constexpr int Bn = 8;
constexpr int Np = 4096;                 // H*W
constexpr int Cc = 256;
constexpr float kEps = 1e-6f;
constexpr float kRsqrt2 = 0.70710678118654752440f;
constexpr int kRows = Bn * Np;           // 32768
}  // namespace

__device__ __forceinline__ u16 f2b(float x) {
  unsigned int u = __float_as_uint(x);
  u += 0x7fffu + ((u >> 16) & 1u);       // round-to-nearest-even
  return (u16)(u >> 16);
}

__device__ __forceinline__ u8 f2fp8(float x) {
  return (u8)(__builtin_amdgcn_cvt_pk_fp8_f32(x, x, 0, false) & 0xff);
}

__device__ __forceinline__ void stage16(const void* g, void* l) {
  __builtin_amdgcn_global_load_lds((const glb_u32*)g, (lds_u32*)l, 16, 0, 0);
}

union V8U {
  uint4 u[2];
  i32x8 v;
};

// ---------------- weight convert: W[c][d] fp32 -> W^T swizzled bf16 tiles ---
__global__ __launch_bounds__(256) void conv_w_k(
    const float* __restrict__ Wq, const float* __restrict__ Wk,
    const float* __restrict__ Wv, const float* __restrict__ Wf,
    u16* __restrict__ wsw) {
  const int w = blockIdx.x;
  const float* W = (w == 0) ? Wq : (w == 1) ? Wk : (w == 2) ? Wv : Wf;
  const int t = threadIdx.x;               // = d (output channel)
  const int nt = t >> 7, r = t & 127;
  for (int c0 = 0; c0 < 32; ++c0) {
    const int c = blockIdx.y * 32 + c0;
    const float val = W[(size_t)c * Cc + t];   // coalesced along t
    const int kt = c >> 6, kk = c & 63;
    const size_t byte = (((size_t)(w * 8 + nt * 4 + kt)) << 14) +
                        (((r * 128 + kk * 2)) ^ ((r & 7) << 4));
    *(u16*)((char*)wsw + byte) = f2b(val);
  }
}

// ---------------- GroupNorm (two-kernel: stats + coalesced apply) ---------
__global__ __launch_bounds__(256) void gn_stats_k(const float* __restrict__ x,
                                                  float* __restrict__ st) {
  const int bg = blockIdx.x;
  const int b = bg >> 5, g = bg & 31;
  const float* base = x + (size_t)b * Np * Cc + g * 8;
  float s = 0.f, ss = 0.f;
  for (int i = threadIdx.x; i < Np * 2; i += 256) {
    const int p = i >> 1, hh = (i & 1) * 4;
    const float4 v = *(const float4*)(base + (size_t)p * Cc + hh);
    s += v.x + v.y + v.z + v.w;
    ss += v.x * v.x + v.y * v.y + v.z * v.z + v.w * v.w;
  }
  __shared__ float red[8];
#pragma unroll
  for (int off = 32; off; off >>= 1) {
    s += __shfl_down(s, off);
    ss += __shfl_down(ss, off);
  }
  const int wid = threadIdx.x >> 6;
  if ((threadIdx.x & 63) == 0) { red[wid] = s; red[wid + 4] = ss; }
  __syncthreads();
  if (threadIdx.x == 0) {
    s = red[0] + red[1] + red[2] + red[3];
    ss = red[4] + red[5] + red[6] + red[7];
    const float mean = s * (1.f / 32768.f);
    const float var = ss * (1.f / 32768.f) - mean * mean;
    st[bg * 2] = mean;
    st[bg * 2 + 1] = rsqrtf(var + kEps);
  }
}

// gn_apply writes h as bf16 SWIZZLED GEMM A-tiles directly (coalesced read).
__global__ __launch_bounds__(256) void gn_apply_k(const float* __restrict__ x,
                                                  const float* __restrict__ st,
                                                  const float* __restrict__ gs,
                                                  const float* __restrict__ gb,
                                                  u16* __restrict__ hsw) {
  const int total = kRows * Cc / 4;
  for (int i = blockIdx.x * blockDim.x + threadIdx.x; i < total;
       i += gridDim.x * blockDim.x) {
    const int c4 = i & 63;
    const int p = i >> 6;
    const int b = p >> 12;
    const int g = c4 >> 1;
    const float mean = st[(b * 32 + g) * 2];
    const float rstd = st[(b * 32 + g) * 2 + 1];
    const float4 xv = ((const float4*)x)[i];
    const float4 sv = ((const float4*)gs)[c4];
    const float4 bv = ((const float4*)gb)[c4];
    ushort4 o;
    o.x = f2b((xv.x - mean) * rstd * sv.x + bv.x);
    o.y = f2b((xv.y - mean) * rstd * sv.y + bv.y);
    o.z = f2b((xv.z - mean) * rstd * sv.z + bv.z);
    o.w = f2b((xv.w - mean) * rstd * sv.w + bv.w);
    const int mt = p >> 7, r = p & 127;
    const int c = c4 * 4, kt = c >> 6, kk = c & 63;
    const size_t byte = (((size_t)(mt * 4 + kt)) << 14) +
                        (((r * 128 + kk * 2)) ^ ((r & 7) << 4));
    *(ushort4*)((char*)hsw + byte) = o;
  }
}

// ---------------- bf16 MFMA GEMM (A_sw [M][K] tiles, W^T_sw tiles) ---------
// mode 0: q = A.Wq + bq -> fp8 rows (UNSCALED; 1/16 folded into attn exp).
// mode 1: k -> fp8 QK-A-fragment tiles, 16KB per 64 keys.
// mode 2: v -> fp8 PV-A-fragment tiles, 16KB per 64 kv.
// mode 3: out = (x + A.Wf + bf)*rsqrt2 fp32.
__global__ __launch_bounds__(256, 2) void gemm_k(
    const u16* __restrict__ A_sw, const u16* __restrict__ wsw,
    const float* __restrict__ bq, const float* __restrict__ bk,
    const float* __restrict__ bv, const float* __restrict__ bf,
    const float* __restrict__ x, u8* __restrict__ qg, u8* __restrict__ kg,
    u8* __restrict__ vtt, float* __restrict__ out, int mode_sel) {
  __shared__ __align__(16) u16 Al[2][8192], Bl[2][8192];
  const int mode = (mode_sel < 0) ? blockIdx.z : mode_sel;
  const int mt0 = blockIdx.x;
  const int nt0 = blockIdx.y;
  const int t = threadIdx.x;
  const int w = t >> 6, l = t & 63;
  const int wm = w >> 1, wn = w & 1;
  const int lr = l & 15, lg = l >> 4;
  f32x4 acc[4][4];
#pragma unroll
  for (int i = 0; i < 4; ++i)
#pragma unroll
    for (int j = 0; j < 4; ++j) acc[i][j] = (f32x4){0.f, 0.f, 0.f, 0.f};

  auto stg = [&](int kt, int nxt) {
    const char* at = (const char*)A_sw + (((size_t)mt0 * 4 + kt) << 14);
    const char* bt =
        (const char*)wsw + (((size_t)(mode * 8 + nt0 * 4 + kt)) << 14);
    char* ad = (char*)&Al[nxt][0];
    char* bd = (char*)&Bl[nxt][0];
#pragma unroll
    for (int p = 0; p < 4; ++p) {
      const int c = p * 256 + t;
      stage16(at + c * 16, ad + c * 16);
      stage16(bt + c * 16, bd + c * 16);
    }
  };

  stg(0, 0);
  __syncthreads();
  for (int kt = 0; kt < 4; ++kt) {
    if (kt < 3) stg(kt + 1, (kt + 1) & 1);
    const char* Ac = (const char*)&Al[kt & 1][0];
    const char* Bc = (const char*)&Bl[kt & 1][0];
    __builtin_amdgcn_s_setprio(1);
#pragma unroll
    for (int ks = 0; ks < 2; ++ks) {
      bf16x8 af[4], bfr[4];
#pragma unroll
      for (int i = 0; i < 4; ++i)
        af[i] = *(const bf16x8*)(
            Ac + (((wm * 64 + i * 16 + lr) * 128 + ks * 64 + lg * 16) ^
                  ((lr & 7) << 4)));
#pragma unroll
      for (int j = 0; j < 4; ++j)
        bfr[j] = *(const bf16x8*)(
            Bc + (((wn * 64 + j * 16 + lr) * 128 + ks * 64 + lg * 16) ^
                  ((lr & 7) << 4)));
#pragma unroll
      for (int i = 0; i < 4; ++i)
#pragma unroll
        for (int j = 0; j < 4; ++j)
          acc[i][j] = __builtin_amdgcn_mfma_f32_16x16x32_bf16(af[i], bfr[j],
                                                              acc[i][j], 0, 0, 0);
    }
    __builtin_amdgcn_s_setprio(0);
    __syncthreads();
  }
  // ---- epilogue ----
  const int m0 = mt0 * 128 + wm * 64;
  const int n0 = nt0 * 128 + wn * 64;
  const float* bias = (mode == 0) ? bq : (mode == 1) ? bk : (mode == 2) ? bv : bf;
  float bv4[4];
#pragma unroll
  for (int j = 0; j < 4; ++j) bv4[j] = bias[n0 + j * 16 + lr];
#pragma unroll
  for (int i = 0; i < 4; ++i)
#pragma unroll
    for (int e = 0; e < 4; ++e) {
      const int m = m0 + i * 16 + lg * 4 + e;
#pragma unroll
      for (int j = 0; j < 4; ++j) {
        const int n = n0 + j * 16 + lr;
        const float val = acc[i][j][e] + bv4[j];
        if (mode == 0) {
          qg[(size_t)m * Cc + n] = f2fp8(val);
        } else if (mode == 1) {
          const size_t pos = ((size_t)(m >> 6)) * 16384 +
                             ((size_t)((m >> 5) & 1)) * 8192 +
                             (n >> 6) * 2048 +
                             ((m & 31) + 32 * ((n >> 5) & 1)) * 32 + (n & 31);
          kg[pos] = f2fp8(val);
        } else if (mode == 2) {
          const int kv = m & 63;
          const size_t pos = ((size_t)(m >> 6)) * 16384 + (n >> 5) * 2048 +
                             ((n & 31) + 32 * ((kv >> 2) & 1)) * 32 +
                             (kv & 3) + 4 * ((kv & 31) >> 3) + 16 * (kv >> 5);
          vtt[pos] = f2fp8(val);
        } else {
          out[(size_t)m * Cc + n] =
              (x[(size_t)m * Cc + n] + val) * kRsqrt2;
        }
      }
    }
}

// ---------------- LDS-free MX-fp8 attention, K-dbuf + SM||QK overlap ------
// Grid: 1024 blocks x 64 threads (1 wave). id: batch = id&7 (XCD pin),
// q-tile (32 rows) = id>>3. 64 key-tiles of 64 keys. Per tile: 8 QK + 8 PV
// mfma_scale_32x32x64 (scale=1.0). K register-double-buffered so QK(t+1)
// sits after SM(t) in one basic block (scheduler overlaps MFMA w/ VALU).
// V8U union loads + setprio fences keep VGPR at 188 (direct i32x8 loads
// force contiguous 8-reg tuples at load time -> 256 cap + spill, R19).
// p = exp(s/16 - 2) no-max softmax (validated R5+).
__global__ __launch_bounds__(64, 1) void attn_mfma_k(
    const u8* __restrict__ qg, const u8* __restrict__ ksw,
    const u8* __restrict__ vsw, u16* __restrict__ h2) {
  const int id = blockIdx.x;
  const int b = id & 7;
  const int qt = id >> 3;                 // 0..127
  const int l = threadIdx.x;
  const int lq = l & 31;
  const int hi = l >> 5;

  const u8* kbase = ksw + (size_t)b * Np * Cc;
  const u8* vbase = vsw + (size_t)b * Np * Cc;

  // Q fragments: MFMA m covers channels m*64 + hi*32 + (0..31)
  i32x8 QF[4];
  {
    const u8* qrow = qg + ((size_t)b * Np + qt * 32 + lq) * Cc;
#pragma unroll
    for (int m = 0; m < 4; ++m) {
      V8U u;
      u.u[0] = *(const uint4*)(qrow + m * 64 + hi * 32);
      u.u[1] = *(const uint4*)(qrow + m * 64 + hi * 32 + 16);
      QF[m] = u.v;
    }
  }
  f32x16 oacc[8];
#pragma unroll
  for (int nb = 0; nb < 8; ++nb)
#pragma unroll
    for (int r = 0; r < 16; ++r) oacc[nb][r] = 0.f;
  float lrow = 0.f;

  i32x8 KA[8], KB[8], VRr[8];   // K: [ (s<<2)|m ]; V: [cb]

  auto loadK = [&](int gt, i32x8* K) {
    const u8* kt = kbase + (size_t)gt * 16384;
#pragma unroll
    for (int i = 0; i < 8; ++i) {
      const u8* p = kt + (i >> 2) * 8192 + (i & 3) * 2048 + l * 32;
      V8U u;
      u.u[0] = *(const uint4*)(p);
      u.u[1] = *(const uint4*)(p + 16);
      K[i] = u.v;
    }
  };
  auto loadV = [&](int gt) {
    const u8* vt = vbase + (size_t)gt * 16384;
#pragma unroll
    for (int cb = 0; cb < 8; ++cb) {
      const u8* p = vt + cb * 2048 + l * 32;
      V8U u;
      u.u[0] = *(const uint4*)(p);
      u.u[1] = *(const uint4*)(p + 16);
      VRr[cb] = u.v;
    }
  };

  // QK: S^T[64 key][32 q], two 4-MFMA chains over 256 channels.
  auto qk = [&](const i32x8* K, f32x16& s0, f32x16& s1) {
#pragma unroll
    for (int r = 0; r < 16; ++r) { s0[r] = 0.f; s1[r] = 0.f; }
    __builtin_amdgcn_s_setprio(1);
#pragma unroll
    for (int m = 0; m < 4; ++m) {
      s0 = __builtin_amdgcn_mfma_scale_f32_32x32x64_f8f6f4(
          K[m], QF[m], s0, 0, 0, 0, 0x7F, 0, 0x7F);
      s1 = __builtin_amdgcn_mfma_scale_f32_32x32x64_f8f6f4(
          K[4 + m], QF[m], s1, 0, 0, 0, 0x7F, 0, 0x7F);
    }
    __builtin_amdgcn_s_setprio(0);
  };

  // softmax + pack: p = exp(s/16 - 2); bytes 0-15 = p0, 16-31 = p1.
  auto smpack = [&](const f32x16& s0, const f32x16& s1, V8U& PP) {
    unsigned int d[8];
#pragma unroll
    for (int g = 0; g < 4; ++g) {
      const float a0 = __expf(s0[4 * g + 0] * 0.0625f - 2.0f);
      const float a1 = __expf(s0[4 * g + 1] * 0.0625f - 2.0f);
      const float a2 = __expf(s0[4 * g + 2] * 0.0625f - 2.0f);
      const float a3 = __expf(s0[4 * g + 3] * 0.0625f - 2.0f);
      lrow += (a0 + a1) + (a2 + a3);
      unsigned int r0 = (unsigned int)__builtin_amdgcn_cvt_pk_fp8_f32(
          a0, a1, 0, false);
      d[g] = (unsigned int)__builtin_amdgcn_cvt_pk_fp8_f32(a2, a3, (int)r0,
                                                           true);
      const float b0 = __expf(s1[4 * g + 0] * 0.0625f - 2.0f);
      const float b1 = __expf(s1[4 * g + 1] * 0.0625f - 2.0f);
      const float b2 = __expf(s1[4 * g + 2] * 0.0625f - 2.0f);
      const float b3 = __expf(s1[4 * g + 3] * 0.0625f - 2.0f);
      lrow += (b0 + b1) + (b2 + b3);
      unsigned int r1 = (unsigned int)__builtin_amdgcn_cvt_pk_fp8_f32(
          b0, b1, 0, false);
      d[4 + g] = (unsigned int)__builtin_amdgcn_cvt_pk_fp8_f32(b2, b3, (int)r1,
                                                               true);
    }
    PP.u[0] = make_uint4(d[0], d[1], d[2], d[3]);
    PP.u[1] = make_uint4(d[4], d[5], d[6], d[7]);
  };

  // PV: O^T[256 ch][32 q] += V^T * P^T (8 independent MFMAs)
  auto pv = [&](const V8U& PP) {
    __builtin_amdgcn_s_setprio(1);
#pragma unroll
    for (int cb = 0; cb < 8; ++cb) {
      oacc[cb] = __builtin_amdgcn_mfma_scale_f32_32x32x64_f8f6f4(
          VRr[cb], PP.v, oacc[cb], 0, 0, 0, 0x7F, 0, 0x7F);
    }
    __builtin_amdgcn_s_setprio(0);
  };

  f32x16 sA0, sA1, sB0, sB1;
  loadK(0, KA);
  loadV(0);
  qk(KA, sA0, sA1);                       // QK(0)
  loadK(1, KB);

  // loop invariant at top: sA = QK(t), KB = K(t+1), VRr = V(t).
  for (int t = 0; t <= 60; t += 2) {
    V8U PP;
    smpack(sA0, sA1, PP);                 // SM(t)   (VALU)
    qk(KB, sB0, sB1);                     // QK(t+1) (MFMA, overlaps SM)
    pv(PP);                               // PV(t)
    loadV(t + 1);
    loadK(t + 2, KA);                     // KA free since QK(t)
    smpack(sB0, sB1, PP);                 // SM(t+1)
    qk(KA, sA0, sA1);                     // QK(t+2)
    pv(PP);                               // PV(t+1)
    loadV(t + 2);
    loadK(t + 3, KB);
  }
  // exit: sA = QK(62), KB = K(63), VRr = V(62).
  {
    V8U PP;
    smpack(sA0, sA1, PP);                 // SM(62)
    qk(KB, sB0, sB1);                     // QK(63)
    pv(PP);                               // PV(62)
    loadV(63);
    smpack(sB0, sB1, PP);                 // SM(63)
    pv(PP);                               // PV(63)
  }

  // ---- epilogue: normalize, store bf16 swizzled A-tiles for final GEMM ----
  lrow += __shfl_xor(lrow, 32);
  const float inv = 1.f / lrow;
  const size_t mt = (size_t)b * 32 + (qt >> 2);
  const int r = (qt & 3) * 32 + lq;
#pragma unroll
  for (int nb = 0; nb < 8; ++nb)
#pragma unroll
    for (int g = 0; g < 4; ++g) {
      const int c = nb * 32 + g * 8 + hi * 4;
      const int kt = c >> 6, kk = c & 63;
      ushort4 val;
      val.x = f2b(oacc[nb][4 * g + 0] * inv);
      val.y = f2b(oacc[nb][4 * g + 1] * inv);
      val.z = f2b(oacc[nb][4 * g + 2] * inv);
      val.w = f2b(oacc[nb][4 * g + 3] * inv);
      const size_t byte =
          ((mt * 4 + kt) << 14) + (((r * 128 + kk * 2)) ^ ((r & 7) << 4));
      *(ushort4*)((char*)h2 + byte) = val;
    }
}

extern "C" void kernel_launch(void* const* d_in, const int* in_sizes, int n_in,
                              void* d_out, int out_size, void* d_ws,
                              size_t ws_size, hipStream_t stream) {
  const float* x = (const float*)d_in[0];
  const float* gs = (const float*)d_in[1];
  const float* gb = (const float*)d_in[2];
  const float* Wq = (const float*)d_in[3];
  const float* bq = (const float*)d_in[4];
  const float* Wk = (const float*)d_in[5];
  const float* bk = (const float*)d_in[6];
  const float* Wv = (const float*)d_in[7];
  const float* bv = (const float*)d_in[8];
  const float* Wf = (const float*)d_in[9];
  const float* bf = (const float*)d_in[10];
  float* out = (float*)d_out;

  // ws: h_sw bf16 | q fp8 | k_sw fp8 | v_sw fp8 | h2_sw bf16 | wsw bf16 | st
  u16* hsw = (u16*)d_ws;
  u8* qg = (u8*)(hsw + (size_t)kRows * Cc);
  u8* kg = qg + (size_t)kRows * Cc;
  u8* vtt = kg + (size_t)kRows * Cc;
  u16* h2 = (u16*)(vtt + (size_t)kRows * Cc);
  u16* wsw = h2 + (size_t)kRows * Cc;
  float* st = (float*)(wsw + 4 * 8 * 8192);

  conv_w_k<<<dim3(4, 8), dim3(256), 0, stream>>>(Wq, Wk, Wv, Wf, wsw);
  gn_stats_k<<<dim3(Bn * 32), dim3(256), 0, stream>>>(x, st);
  gn_apply_k<<<dim3(1024), dim3(256), 0, stream>>>(x, st, gs, gb, hsw);
  gemm_k<<<dim3(kRows / 128, Cc / 128, 3), dim3(256), 0, stream>>>(
      hsw, wsw, bq, bk, bv, bf, x, qg, kg, vtt, out, -1);
  attn_mfma_k<<<dim3(1024), dim3(64), 0, stream>>>(qg, kg, vtt, h2);
  gemm_k<<<dim3(kRows / 128, Cc / 128, 1), dim3(256), 0, stream>>>(
      h2, wsw, bq, bk, bv, bf, x, qg, kg, vtt, out, 3);
}